// Round 11
// baseline (128.900 us; speedup 1.0000x reference)
//
#include <hip/hip_runtime.h>

#define BB 16
#define HH 512
#define WW 512
#define TH 32
#define TW 64
#define HALO 8
#define SR 49                 // staged rows = TH + 2*HALO + 1
#define SC 80                 // staged cols (px)
#define SSTRIDE 81            // LDS slots per row (odd -> bank-pair spread)
#define ROWQ (SC / 4)         // 20 quad-px staging units per row
#define NUNIT (SR * ROWQ)     // 980
#define NPIX (BB * HH * WW)

typedef float vf4 __attribute__((ext_vector_type(4)));
typedef unsigned int u32;
typedef u32 vu2 __attribute__((ext_vector_type(2)));

__device__ __forceinline__ u32 cvt_pk_bf16(float lo, float hi) {
    u32 r;
    asm("v_cvt_pk_bf16_f32 %0, %1, %2" : "=v"(r) : "v"(lo), "v"(hi));
    return r;   // low16 = bf16(lo), high16 = bf16(hi), RNE
}
__device__ __forceinline__ float bf_lo(u32 w) { return __uint_as_float(w << 16); }
__device__ __forceinline__ float bf_hi(u32 w) { return __uint_as_float(w & 0xffff0000u); }

__global__ __launch_bounds__(256, 5) void warp2_kernel(
    const float* __restrict__ frame0,
    const float* __restrict__ frame1,
    const float* __restrict__ f01,
    const float* __restrict__ f10,
    float* __restrict__ out)
{
    __shared__ vu2 plds[SR * SSTRIDE];   // 49*81*8 = 31,752 B -> 5 blocks/CU

    // ---- tile decode, bijective XCD-chunked swizzle (4096 = 8 * 512) ----
    const int bid = blockIdx.x;
    const int gt  = (bid & 7) * 512 + (bid >> 3);
    const int which = gt >> 11;          // 2048 tiles per output
    const int b     = (gt >> 7) & 15;
    const int tt    = gt & 127;
    const int ty    = (tt >> 3) * TH;    // 16 rowtiles
    const int tx    = (tt & 7) * TW;     // 8 coltiles, fastest -> L2 reuse

    const float* __restrict__ img  = which ? frame1 : frame0;
    const float* __restrict__ flow = which ? f01    : f10;

    const int r0 = min(max(ty - HALO, 0), HH - SR);
    const int c0 = min(max(tx - HALO, 0), WW - SC);

    const int tid = threadIdx.x;

    // ---- per-thread output strip: 8 consecutive px ----
    const int r  = tid >> 3;             // 0..31 row in tile
    const int k  = tid & 7;              // 0..7 octet in row
    const int y  = ty + r;
    const int xq = tx + (k << 3);        // first of 8 px
    const size_t pixbase = (size_t)(b * HH + y) * WW + xq;

    // ---- flow prefetch: 16 floats (latency hides under staging) ----
    const vf4 fA = __builtin_nontemporal_load(reinterpret_cast<const vf4*>(flow + 2 * pixbase));
    const vf4 fB = __builtin_nontemporal_load(reinterpret_cast<const vf4*>(flow + 2 * pixbase + 4));
    const vf4 fC = __builtin_nontemporal_load(reinterpret_cast<const vf4*>(flow + 2 * pixbase + 8));
    const vf4 fD = __builtin_nontemporal_load(reinterpret_cast<const vf4*>(flow + 2 * pixbase + 12));

    // ---- stage 980 quad-px units as packed bf16 (8 B/px) ----
    #pragma unroll
    for (int it = 0; it < 4; ++it) {
        const int s = tid + (it << 8);
        if (it < 3 || s < NUNIT) {
            const int row = s / ROWQ;                 // const divisor -> magic mul
            const int u   = s - row * ROWQ;
            const float* g = img + ((size_t)((b * HH + r0 + row) * WW + c0 + (u << 2))) * 3;
            const vf4 a0 = *reinterpret_cast<const vf4*>(g);      // R0 G0 B0 R1
            const vf4 a1 = *reinterpret_cast<const vf4*>(g + 4);  // G1 B1 R2 G2
            const vf4 a2 = *reinterpret_cast<const vf4*>(g + 8);  // B2 R3 G3 B3
            const int base = row * SSTRIDE + (u << 2);
            plds[base]     = (vu2){ cvt_pk_bf16(a0.x, a0.y), cvt_pk_bf16(a0.z, 0.0f) };
            plds[base + 1] = (vu2){ cvt_pk_bf16(a0.w, a1.x), cvt_pk_bf16(a1.y, 0.0f) };
            plds[base + 2] = (vu2){ cvt_pk_bf16(a1.z, a1.w), cvt_pk_bf16(a2.x, 0.0f) };
            plds[base + 3] = (vu2){ cvt_pk_bf16(a2.y, a2.z), cvt_pk_bf16(a2.w, 0.0f) };
        }
    }
    __syncthreads();

    // ---- gather: 8 independent px chains per thread ----
    float res[24];
    #pragma unroll
    for (int s = 0; s < 8; ++s) {
        const vf4 fv = (s < 2) ? fA : (s < 4) ? fB : (s < 6) ? fC : fD;
        const float dy = (s & 1) ? fv.z : fv.x;
        const float dx = (s & 1) ? fv.w : fv.y;
        const int xs = xq + s;

        const float qy = (float)y  - dy;
        const float qx = (float)xs - dx;
        const float y0f = fminf(fmaxf(floorf(qy), 0.0f), (float)(HH - 2));
        const float x0f = fminf(fmaxf(floorf(qx), 0.0f), (float)(WW - 2));
        const float ay = fminf(fmaxf(qy - y0f, 0.0f), 1.0f);
        const float ax = fminf(fmaxf(qx - x0f, 0.0f), 1.0f);
        const int y0 = (int)y0f;
        const int x0 = (int)x0f;

        float tl0, tl1, tl2, tr0, tr1, tr2, bl0, bl1, bl2, br0, br1, br2;
        if (y0 >= r0 && y0 < r0 + SR - 1 && x0 >= c0 && x0 < c0 + SC - 1) {
            const int o = (y0 - r0) * SSTRIDE + (x0 - c0);
            // tl/tr adjacent 8B slots, bl/br adjacent -> ds_read2_b64 pairs
            const vu2 tl = plds[o];            const vu2 tr = plds[o + 1];
            const vu2 bl = plds[o + SSTRIDE];  const vu2 br = plds[o + SSTRIDE + 1];
            tl0 = bf_lo(tl.x); tl1 = bf_hi(tl.x); tl2 = bf_lo(tl.y);
            tr0 = bf_lo(tr.x); tr1 = bf_hi(tr.x); tr2 = bf_lo(tr.y);
            bl0 = bf_lo(bl.x); bl1 = bf_hi(bl.x); bl2 = bf_lo(bl.y);
            br0 = bf_lo(br.x); br1 = bf_hi(br.x); br2 = bf_lo(br.y);
        } else {
            // |flow| > HALO outlier (P ~ 1e-12): exact fp32 fallback from global
            const float* rowt = img + ((size_t)((b * HH + y0) * WW + x0)) * 3;
            const float* rowb = rowt + WW * 3;
            const float3 tl = *reinterpret_cast<const float3*>(rowt);
            const float3 tr = *reinterpret_cast<const float3*>(rowt + 3);
            const float3 bl = *reinterpret_cast<const float3*>(rowb);
            const float3 br = *reinterpret_cast<const float3*>(rowb + 3);
            tl0 = tl.x; tl1 = tl.y; tl2 = tl.z;
            tr0 = tr.x; tr1 = tr.y; tr2 = tr.z;
            bl0 = bl.x; bl1 = bl.y; bl2 = bl.z;
            br0 = br.x; br1 = br.y; br2 = br.z;
        }

        const float t0 = fmaf(ax, tr0 - tl0, tl0);
        const float t1 = fmaf(ax, tr1 - tl1, tl1);
        const float t2 = fmaf(ax, tr2 - tl2, tl2);
        const float q0 = fmaf(ax, br0 - bl0, bl0);
        const float q1 = fmaf(ax, br1 - bl1, bl1);
        const float q2 = fmaf(ax, br2 - bl2, bl2);
        res[3 * s + 0] = fmaf(ay, q0 - t0, t0);
        res[3 * s + 1] = fmaf(ay, q1 - t1, t1);
        res[3 * s + 2] = fmaf(ay, q2 - t2, t2);
    }

    // ---- store 8 px = 96B contiguous, 16B-aligned ----
    float* o = out + 3 * (((size_t)which) * NPIX + pixbase);
    #pragma unroll
    for (int v = 0; v < 6; ++v) {
        const vf4 sv = {res[4 * v], res[4 * v + 1], res[4 * v + 2], res[4 * v + 3]};
        *reinterpret_cast<vf4*>(o + 4 * v) = sv;
    }
}

extern "C" void kernel_launch(void* const* d_in, const int* in_sizes, int n_in,
                              void* d_out, int out_size, void* d_ws, size_t ws_size,
                              hipStream_t stream) {
    const float* frame0 = (const float*)d_in[0];
    const float* frame1 = (const float*)d_in[1];
    const float* f01    = (const float*)d_in[2];
    const float* f10    = (const float*)d_in[3];
    float* out = (float*)d_out;

    // 2 outputs * 16 batches * 16 rowtiles * 8 coltiles = 4096 blocks
    warp2_kernel<<<4096, 256, 0, stream>>>(frame0, frame1, f01, f10, out);
}

// Round 12
// 51.403 us; speedup vs baseline: 2.5076x; 2.5076x over previous
//
#include <hip/hip_runtime.h>

#define BB 16
#define HH 512
#define WW 512
#define TH 16
#define TW 64
#define HALO 8
#define SR 33                 // staged rows = TH + 2*HALO + 1
#define SC 80                 // staged cols (px) = LDS row stride (slots)
#define ROWQ (SC / 4)         // 20 quad-px staging units per row
#define NUNIT (SR * ROWQ)     // 660
#define NPIX (BB * HH * WW)

typedef float vf4 __attribute__((ext_vector_type(4)));
typedef float vf2 __attribute__((ext_vector_type(2)));
typedef unsigned int u32;
typedef u32 vu4 __attribute__((ext_vector_type(4)));
typedef u32 vu2 __attribute__((ext_vector_type(2)));

__device__ __forceinline__ u32 cvt_pk_bf16(float lo, float hi) {
    u32 r;
    asm("v_cvt_pk_bf16_f32 %0, %1, %2" : "=v"(r) : "v"(lo), "v"(hi));
    return r;   // low16 = bf16(lo), high16 = bf16(hi), RNE
}
__device__ __forceinline__ float bf_lo(u32 w) { return __uint_as_float(w << 16); }
__device__ __forceinline__ float bf_hi(u32 w) { return __uint_as_float(w & 0xffff0000u); }

__global__ __launch_bounds__(256, 7) void warp2_kernel(
    const float* __restrict__ frame0,
    const float* __restrict__ frame1,
    const float* __restrict__ f01,
    const float* __restrict__ f10,
    float* __restrict__ out)
{
    __shared__ vu2 plds[SR * SC];        // 21,120 B -> 7 blocks/CU

    // ---- tile decode, bijective XCD-chunked swizzle (8192 = 8 * 1024) ----
    const int bid = blockIdx.x;
    const int gt  = (bid & 7) * 1024 + (bid >> 3);
    const int which = gt >> 12;          // 4096 tiles per output
    const int b     = (gt >> 8) & 15;
    const int tt    = gt & 255;
    const int ty    = (tt >> 3) * TH;    // 32 rowtiles
    const int tx    = (tt & 7) * TW;     // 8 coltiles, fastest -> L2 reuse

    const float* __restrict__ img  = which ? frame1 : frame0;
    const float* __restrict__ flow = which ? f01    : f10;

    const int r0 = min(max(ty - HALO, 0), HH - SR);
    const int c0 = min(max(tx - HALO, 0), WW - SC);

    const int tid = threadIdx.x;

    // ---- strided pixel ownership: lane (r,q) owns x = tx + q + 16*s, s=0..3 ----
    const int r = tid >> 4;              // 0..15 row in tile
    const int q = tid & 15;              // lane within row group
    const int y = ty + r;
    const size_t rowpix = (size_t)(b * HH + y) * WW;

    // ---- flow prefetch: 4 wave-coalesced 8B loads (latency hides under staging) ----
    vf2 fl[4];
    #pragma unroll
    for (int s = 0; s < 4; ++s)
        fl[s] = __builtin_nontemporal_load(
            reinterpret_cast<const vf2*>(flow + 2 * (rowpix + tx + q + (s << 4))));

    // ---- stage 660 quad-px units as packed bf16 (8 B/px), vu4 16B writes ----
    #pragma unroll
    for (int it = 0; it < 3; ++it) {
        const int s = tid + (it << 8);
        if (it < 2 || s < NUNIT) {
            const int row = s / ROWQ;                 // const divisor -> magic mul
            const int u   = s - row * ROWQ;
            const float* g = img + ((size_t)((b * HH + r0 + row) * WW + c0 + (u << 2))) * 3;
            const vf4 a0 = *reinterpret_cast<const vf4*>(g);      // R0 G0 B0 R1
            const vf4 a1 = *reinterpret_cast<const vf4*>(g + 4);  // G1 B1 R2 G2
            const vf4 a2 = *reinterpret_cast<const vf4*>(g + 8);  // B2 R3 G3 B3
            const vu4 w0 = { cvt_pk_bf16(a0.x, a0.y), cvt_pk_bf16(a0.z, 0.0f),
                             cvt_pk_bf16(a0.w, a1.x), cvt_pk_bf16(a1.y, 0.0f) };
            const vu4 w1 = { cvt_pk_bf16(a1.z, a1.w), cvt_pk_bf16(a2.x, 0.0f),
                             cvt_pk_bf16(a2.y, a2.z), cvt_pk_bf16(a2.w, 0.0f) };
            const int base = row * SC + (u << 2);     // even -> 16B-aligned
            *reinterpret_cast<vu4*>(&plds[base])     = w0;
            *reinterpret_cast<vu4*>(&plds[base + 2]) = w1;
        }
    }
    __syncthreads();

    // ---- gather: 4 independent chains, lanes read CONSECUTIVE LDS slots ----
    #pragma unroll
    for (int s = 0; s < 4; ++s) {
        const int x = tx + q + (s << 4);
        const float dy = fl[s].x;
        const float dx = fl[s].y;

        const float qy = (float)y - dy;
        const float qx = (float)x - dx;
        const float y0f = fminf(fmaxf(floorf(qy), 0.0f), (float)(HH - 2));
        const float x0f = fminf(fmaxf(floorf(qx), 0.0f), (float)(WW - 2));
        const float ay = fminf(fmaxf(qy - y0f, 0.0f), 1.0f);
        const float ax = fminf(fmaxf(qx - x0f, 0.0f), 1.0f);
        const int y0 = (int)y0f;
        const int x0 = (int)x0f;

        float tl0, tl1, tl2, tr0, tr1, tr2, bl0, bl1, bl2, br0, br1, br2;
        if (y0 >= r0 && y0 < r0 + SR - 1 && x0 >= c0 && x0 < c0 + SC - 1) {
            const int o = (y0 - r0) * SC + (x0 - c0);
            const vu2 tl = plds[o];       const vu2 tr = plds[o + 1];
            const vu2 bl = plds[o + SC];  const vu2 br = plds[o + SC + 1];
            tl0 = bf_lo(tl.x); tl1 = bf_hi(tl.x); tl2 = bf_lo(tl.y);
            tr0 = bf_lo(tr.x); tr1 = bf_hi(tr.x); tr2 = bf_lo(tr.y);
            bl0 = bf_lo(bl.x); bl1 = bf_hi(bl.x); bl2 = bf_lo(bl.y);
            br0 = bf_lo(br.x); br1 = bf_hi(br.x); br2 = bf_lo(br.y);
        } else {
            // |flow| > HALO outlier (P ~ 1e-12): exact fp32 fallback from global
            const float* rowt = img + ((size_t)((b * HH + y0) * WW + x0)) * 3;
            const float* rowb = rowt + WW * 3;
            const float3 tl = *reinterpret_cast<const float3*>(rowt);
            const float3 tr = *reinterpret_cast<const float3*>(rowt + 3);
            const float3 bl = *reinterpret_cast<const float3*>(rowb);
            const float3 br = *reinterpret_cast<const float3*>(rowb + 3);
            tl0 = tl.x; tl1 = tl.y; tl2 = tl.z;
            tr0 = tr.x; tr1 = tr.y; tr2 = tr.z;
            bl0 = bl.x; bl1 = bl.y; bl2 = bl.z;
            br0 = br.x; br1 = br.y; br2 = br.z;
        }

        const float t0 = fmaf(ax, tr0 - tl0, tl0);
        const float t1 = fmaf(ax, tr1 - tl1, tl1);
        const float t2 = fmaf(ax, tr2 - tl2, tl2);
        const float g0 = fmaf(ax, br0 - bl0, bl0);
        const float g1 = fmaf(ax, br1 - bl1, bl1);
        const float g2 = fmaf(ax, br2 - bl2, bl2);

        // wave-coalesced 12B store (lanes consecutive -> 192B per row group)
        float* o = out + 3 * (((size_t)which) * NPIX + rowpix + x);
        *reinterpret_cast<float3*>(o) =
            make_float3(fmaf(ay, g0 - t0, t0), fmaf(ay, g1 - t1, t1), fmaf(ay, g2 - t2, t2));
    }
}

extern "C" void kernel_launch(void* const* d_in, const int* in_sizes, int n_in,
                              void* d_out, int out_size, void* d_ws, size_t ws_size,
                              hipStream_t stream) {
    const float* frame0 = (const float*)d_in[0];
    const float* frame1 = (const float*)d_in[1];
    const float* f01    = (const float*)d_in[2];
    const float* f10    = (const float*)d_in[3];
    float* out = (float*)d_out;

    // 2 outputs * 16 batches * 32 rowtiles * 8 coltiles = 8192 blocks
    warp2_kernel<<<8192, 256, 0, stream>>>(frame0, frame1, f01, f10, out);
}

// Round 13
// 46.616 us; speedup vs baseline: 2.7651x; 1.1027x over previous
//
#include <hip/hip_runtime.h>

#define BB 16
#define HH 512
#define WW 512
#define TH 32
#define TW 64
#define HALO 8
#define SR 49                 // staged rows = TH + 2*HALO + 1
#define SC 80                 // staged cols (px) = LDS row stride (slots)
#define ROWQ (SC / 4)         // 20 quad-px staging units per row
#define NUNIT (SR * ROWQ)     // 980
#define NPIX (BB * HH * WW)

typedef float vf4 __attribute__((ext_vector_type(4)));
typedef float vf2 __attribute__((ext_vector_type(2)));
typedef unsigned int u32;
typedef u32 vu4 __attribute__((ext_vector_type(4)));
typedef u32 vu2 __attribute__((ext_vector_type(2)));

__device__ __forceinline__ u32 cvt_pk_bf16(float lo, float hi) {
    u32 r;
    asm("v_cvt_pk_bf16_f32 %0, %1, %2" : "=v"(r) : "v"(lo), "v"(hi));
    return r;   // low16 = bf16(lo), high16 = bf16(hi), RNE
}
__device__ __forceinline__ float bf_lo(u32 w) { return __uint_as_float(w << 16); }
__device__ __forceinline__ float bf_hi(u32 w) { return __uint_as_float(w & 0xffff0000u); }

__global__ __launch_bounds__(512, 8) void warp2_kernel(
    const float* __restrict__ frame0,
    const float* __restrict__ frame1,
    const float* __restrict__ f01,
    const float* __restrict__ f10,
    float* __restrict__ out)
{
    __shared__ vu2 plds[SR * SC];        // 49*80*8 = 31,360 B -> 4 blocks/CU = 32 waves

    // ---- tile decode, bijective XCD-chunked swizzle (4096 = 8 * 512) ----
    const int bid = blockIdx.x;
    const int gt  = (bid & 7) * 512 + (bid >> 3);
    const int which = gt >> 11;          // 2048 tiles per output
    const int b     = (gt >> 7) & 15;
    const int tt    = gt & 127;
    const int ty    = (tt >> 3) * TH;    // 16 rowtiles
    const int tx    = (tt & 7) * TW;     // 8 coltiles, fastest -> L2 reuse

    const float* __restrict__ img  = which ? frame1 : frame0;
    const float* __restrict__ flow = which ? f01    : f10;

    const int r0 = min(max(ty - HALO, 0), HH - SR);
    const int c0 = min(max(tx - HALO, 0), WW - SC);

    const int tid = threadIdx.x;         // 0..511

    // ---- strided pixel ownership: lane (r,q) owns x = tx + q + 16*s, s=0..3 ----
    const int r = tid >> 4;              // 0..31 row in tile
    const int q = tid & 15;              // lane within row group
    const int y = ty + r;
    const size_t rowpix = (size_t)(b * HH + y) * WW;

    // ---- flow prefetch: 4 wave-coalesced 8B loads (latency hides under staging) ----
    vf2 fl[4];
    #pragma unroll
    for (int s = 0; s < 4; ++s)
        fl[s] = __builtin_nontemporal_load(
            reinterpret_cast<const vf2*>(flow + 2 * (rowpix + tx + q + (s << 4))));

    // ---- stage 980 quad-px units as packed bf16 (8 B/px), vu4 16B writes ----
    #pragma unroll
    for (int it = 0; it < 2; ++it) {
        const int s = tid + (it << 9);
        if (it < 1 || s < NUNIT) {
            const int row = s / ROWQ;                 // const divisor -> magic mul
            const int u   = s - row * ROWQ;
            const float* g = img + ((size_t)((b * HH + r0 + row) * WW + c0 + (u << 2))) * 3;
            const vf4 a0 = *reinterpret_cast<const vf4*>(g);      // R0 G0 B0 R1
            const vf4 a1 = *reinterpret_cast<const vf4*>(g + 4);  // G1 B1 R2 G2
            const vf4 a2 = *reinterpret_cast<const vf4*>(g + 8);  // B2 R3 G3 B3
            const vu4 w0 = { cvt_pk_bf16(a0.x, a0.y), cvt_pk_bf16(a0.z, 0.0f),
                             cvt_pk_bf16(a0.w, a1.x), cvt_pk_bf16(a1.y, 0.0f) };
            const vu4 w1 = { cvt_pk_bf16(a1.z, a1.w), cvt_pk_bf16(a2.x, 0.0f),
                             cvt_pk_bf16(a2.y, a2.z), cvt_pk_bf16(a2.w, 0.0f) };
            const int base = row * SC + (u << 2);     // even -> 16B-aligned
            *reinterpret_cast<vu4*>(&plds[base])     = w0;
            *reinterpret_cast<vu4*>(&plds[base + 2]) = w1;
        }
    }
    __syncthreads();

    // ---- gather: 4 independent chains, lanes read consecutive LDS slots ----
    #pragma unroll
    for (int s = 0; s < 4; ++s) {
        const int x = tx + q + (s << 4);
        const float dy = fl[s].x;
        const float dx = fl[s].y;

        const float qy = (float)y - dy;
        const float qx = (float)x - dx;
        const float y0f = fminf(fmaxf(floorf(qy), 0.0f), (float)(HH - 2));
        const float x0f = fminf(fmaxf(floorf(qx), 0.0f), (float)(WW - 2));
        const float ay = fminf(fmaxf(qy - y0f, 0.0f), 1.0f);
        const float ax = fminf(fmaxf(qx - x0f, 0.0f), 1.0f);
        const int y0 = (int)y0f;
        const int x0 = (int)x0f;

        float tl0, tl1, tl2, tr0, tr1, tr2, bl0, bl1, bl2, br0, br1, br2;
        if (y0 >= r0 && y0 < r0 + SR - 1 && x0 >= c0 && x0 < c0 + SC - 1) {
            const int o = (y0 - r0) * SC + (x0 - c0);
            const vu2 tl = plds[o];       const vu2 tr = plds[o + 1];
            const vu2 bl = plds[o + SC];  const vu2 br = plds[o + SC + 1];
            tl0 = bf_lo(tl.x); tl1 = bf_hi(tl.x); tl2 = bf_lo(tl.y);
            tr0 = bf_lo(tr.x); tr1 = bf_hi(tr.x); tr2 = bf_lo(tr.y);
            bl0 = bf_lo(bl.x); bl1 = bf_hi(bl.x); bl2 = bf_lo(bl.y);
            br0 = bf_lo(br.x); br1 = bf_hi(br.x); br2 = bf_lo(br.y);
        } else {
            // |flow| > HALO outlier (P ~ 1e-12): exact fp32 fallback from global
            const float* rowt = img + ((size_t)((b * HH + y0) * WW + x0)) * 3;
            const float* rowb = rowt + WW * 3;
            const float3 tl = *reinterpret_cast<const float3*>(rowt);
            const float3 tr = *reinterpret_cast<const float3*>(rowt + 3);
            const float3 bl = *reinterpret_cast<const float3*>(rowb);
            const float3 br = *reinterpret_cast<const float3*>(rowb + 3);
            tl0 = tl.x; tl1 = tl.y; tl2 = tl.z;
            tr0 = tr.x; tr1 = tr.y; tr2 = tr.z;
            bl0 = bl.x; bl1 = bl.y; bl2 = bl.z;
            br0 = br.x; br1 = br.y; br2 = br.z;
        }

        const float t0 = fmaf(ax, tr0 - tl0, tl0);
        const float t1 = fmaf(ax, tr1 - tl1, tl1);
        const float t2 = fmaf(ax, tr2 - tl2, tl2);
        const float g0 = fmaf(ax, br0 - bl0, bl0);
        const float g1 = fmaf(ax, br1 - bl1, bl1);
        const float g2 = fmaf(ax, br2 - bl2, bl2);

        // wave-coalesced 12B store (lanes consecutive -> 192B per row group)
        float* o = out + 3 * (((size_t)which) * NPIX + rowpix + x);
        *reinterpret_cast<float3*>(o) =
            make_float3(fmaf(ay, g0 - t0, t0), fmaf(ay, g1 - t1, t1), fmaf(ay, g2 - t2, t2));
    }
}

extern "C" void kernel_launch(void* const* d_in, const int* in_sizes, int n_in,
                              void* d_out, int out_size, void* d_ws, size_t ws_size,
                              hipStream_t stream) {
    const float* frame0 = (const float*)d_in[0];
    const float* frame1 = (const float*)d_in[1];
    const float* f01    = (const float*)d_in[2];
    const float* f10    = (const float*)d_in[3];
    float* out = (float*)d_out;

    // 2 outputs * 16 batches * 16 rowtiles * 8 coltiles = 4096 blocks
    warp2_kernel<<<4096, 512, 0, stream>>>(frame0, frame1, f01, f10, out);
}